// Round 3
// baseline (231.482 us; speedup 1.0000x reference)
//
#include <hip/hip_runtime.h>
#include <math.h>

#define HEADS 8
#define DIM 16
#define NPB 32   // nodes per block = 256 threads / 8 lanes-per-node
// q,k,v layout: (N, D, H) -> flat idx within row: d*8 + h, row = 128 floats (512B)
// Lane l of a node-group owns flat positions {32r + 4l + j : r=0..3, j=0..3}.
// Head of element (l,j): (4l + j) & 7  -> parity(l) ? 4+j : j.

__global__ __launch_bounds__(256) void spmha_kernel(
    const float* __restrict__ q, const float* __restrict__ k, const float* __restrict__ v,
    const int* __restrict__ row, const int* __restrict__ col,
    float* __restrict__ out, int N, int E) {
  __shared__ int rp[NPB + 1];

  int node0 = blockIdx.x * NPB;

  // Build this block's row_ptr slice via binary search (row is sorted).
  if (threadIdx.x <= NPB) {
    int target = node0 + threadIdx.x;
    int lo = 0, hi = E;
    while (lo < hi) {
      int mid = (lo + hi) >> 1;
      if (row[mid] < target) lo = mid + 1; else hi = mid;
    }
    rp[threadIdx.x] = lo;
  }
  __syncthreads();

  int il = threadIdx.x >> 3;       // node within block
  int i  = node0 + il;             // global node
  int l  = threadIdx.x & 7;        // lane within 8-lane node-group
  bool alive = (i < N);

  int s = alive ? rp[il] : 0;
  int e = alive ? rp[il + 1] : 0;

  // Cooperative q load: lane l takes float4s at row offsets 8r + l.
  float qv[16];
  if (alive) {
    const float4* qb = (const float4*)(q + (size_t)i * 128);
#pragma unroll
    for (int r = 0; r < 4; ++r) *(float4*)&qv[4 * r] = qb[8 * r + l];
  }

  float o[16];
#pragma unroll
  for (int x = 0; x < 16; ++x) o[x] = 0.f;
  float m[4], den[4];
#pragma unroll
  for (int j = 0; j < 4; ++j) { m[j] = -INFINITY; den[j] = 0.f; }

  auto do_edge = [&](const float* kk, const float* vv) {
    // Per-lane partial dot for its 4 (head-slot) positions.
    float part[4];
#pragma unroll
    for (int j = 0; j < 4; ++j) part[j] = 0.f;
#pragma unroll
    for (int r = 0; r < 4; ++r)
#pragma unroll
      for (int j = 0; j < 4; ++j)
        part[j] = fmaf(qv[4 * r + j], kk[4 * r + j], part[j]);
    // Butterfly over same-parity lanes {l, l^2, l^4, l^6} -> full per-head logits.
#pragma unroll
    for (int j = 0; j < 4; ++j) {
      part[j] += __shfl_xor(part[j], 2);
      part[j] += __shfl_xor(part[j], 4);
    }
    // Online softmax per head-slot j; p[j] matches this lane's own v elements.
#pragma unroll
    for (int j = 0; j < 4; ++j) {
      float mn = fmaxf(m[j], part[j]);
      float sc = __expf(m[j] - mn);     // first edge: exp(-inf) = 0
      float p  = __expf(part[j] - mn);
      den[j] = fmaf(den[j], sc, p);
      m[j] = mn;
#pragma unroll
      for (int r = 0; r < 4; ++r)
        o[4 * r + j] = fmaf(o[4 * r + j], sc, p * vv[4 * r + j]);
    }
  };

  int eidx = s;
  // 2x unrolled: two edges' gathers in flight per waitcnt window.
  for (; eidx + 2 <= e; eidx += 2) {
    int c0 = col[eidx];
    int c1 = col[eidx + 1];
    const float4* kb0 = (const float4*)(k + (size_t)c0 * 128);
    const float4* vb0 = (const float4*)(v + (size_t)c0 * 128);
    const float4* kb1 = (const float4*)(k + (size_t)c1 * 128);
    const float4* vb1 = (const float4*)(v + (size_t)c1 * 128);
    float kk0[16], vv0[16], kk1[16], vv1[16];
#pragma unroll
    for (int r = 0; r < 4; ++r) {
      *(float4*)&kk0[4 * r] = kb0[8 * r + l];
      *(float4*)&vv0[4 * r] = vb0[8 * r + l];
      *(float4*)&kk1[4 * r] = kb1[8 * r + l];
      *(float4*)&vv1[4 * r] = vb1[8 * r + l];
    }
    do_edge(kk0, vv0);
    do_edge(kk1, vv1);
  }
  if (eidx < e) {
    int c0 = col[eidx];
    const float4* kb0 = (const float4*)(k + (size_t)c0 * 128);
    const float4* vb0 = (const float4*)(v + (size_t)c0 * 128);
    float kk0[16], vv0[16];
#pragma unroll
    for (int r = 0; r < 4; ++r) {
      *(float4*)&kk0[4 * r] = kb0[8 * r + l];
      *(float4*)&vv0[4 * r] = vb0[8 * r + l];
    }
    do_edge(kk0, vv0);
  }

  if (alive) {
    float inv[4];
#pragma unroll
    for (int j = 0; j < 4; ++j) inv[j] = (e > s) ? 1.f / den[j] : 0.f;
    float4* ob = (float4*)(out + (size_t)i * 128);
#pragma unroll
    for (int r = 0; r < 4; ++r) {
      float4 res;
      res.x = o[4 * r + 0] * inv[0];
      res.y = o[4 * r + 1] * inv[1];
      res.z = o[4 * r + 2] * inv[2];
      res.w = o[4 * r + 3] * inv[3];
      ob[8 * r + l] = res;
    }
  }
}

extern "C" void kernel_launch(void* const* d_in, const int* in_sizes, int n_in,
                              void* d_out, int out_size, void* d_ws, size_t ws_size,
                              hipStream_t stream) {
  const float* q   = (const float*)d_in[0];
  const float* k   = (const float*)d_in[1];
  const float* v   = (const float*)d_in[2];
  const int*   row = (const int*)d_in[3];
  const int*   col = (const int*)d_in[4];
  float* out = (float*)d_out;

  int N = in_sizes[0] / (DIM * HEADS);
  int E = in_sizes[3];

  int total = N * HEADS;
  int grid = (total + 255) / 256;
  spmha_kernel<<<grid, 256, 0, stream>>>(q, k, v, row, col, out, N, E);
}